// Round 5
// baseline (391.902 us; speedup 1.0000x reference)
//
#include <hip/hip_runtime.h>

// PatchMatch brute-force NN: s,t (4,16,64,64) fp32, patch 3x3 replicate-pad.
// Descriptor dim K = 16*9 = 144. Per batch: 4096 queries vs 4096 targets.
// d2(i,j) = qn_i - 2*cross(i,j) + pn_j, argmin_j per i (ties -> smallest j).
// Outputs (concat flat, ALL FLOAT32): nnf (4,2,64,64) then nnd (4,1,64,64).
//
// R5 vs R4:
//  - staging stores are aligned ds_write_b128 (R4's +1-shifted scalar stores
//    were 8-way bank-conflicted: all v.x in banks ===1 mod 4). We load the
//    shifted window from global (4B-aligned float4 at x=4s-1, legal on CDNA
//    VMEM) so the LDS store is 16B-aligned.
//  - #pragma unroll 1 on the c-loop: full unroll was ~40KB of code, blowing
//    the 32KB L1I. Body now ~2.5KB.

#define N_  4
#define C_  16
#define H_  64
#define W_  64
#define HW_ 4096
#define SPLITS 4
#define TILES_PER_SPLIT 4     // 16 j-tiles (of 256 targets) / 4 splits

__device__ __forceinline__ int iclamp(int v, int lo, int hi) {
    return v < lo ? lo : (v > hi ? hi : v);
}

// Load the float4 covering padded slots [4*seg .. 4*seg+3] of a 64-float
// global row g[0..63] with replicate padding (slot = x+1; slot0 = left clamp,
// slot65 = right clamp, slots 66/67 junk).
__device__ __forceinline__ float4 load_padded_seg(const float* __restrict__ g,
                                                  int seg) {
    if (seg == 0) {
        const float4 a = *(const float4*)g;            // x 0..3
        return make_float4(a.x, a.x, a.y, a.z);        // x -1,0,1,2
    } else if (seg == 16) {
        const float4 a = *(const float4*)(g + 60);     // x 60..63
        return make_float4(a.w, a.w, a.w, a.w);        // x 63,64(clamp),junk
    }
    return *(const float4*)(g + 4 * seg - 1);          // x 4s-1..4s+2
}

// ---------------------------------------------------------------------------
// Kernel 1: pn[n][4096] from t, qn[n][4096] from s  (32768 threads)
// ---------------------------------------------------------------------------
__global__ __launch_bounds__(256)
void prep_norms_kernel(const float* __restrict__ s,
                       const float* __restrict__ t,
                       float* __restrict__ pn,
                       float* __restrict__ qn) {
    const int gid   = blockIdx.x * 256 + threadIdx.x;   // 0..32767
    const int which = gid >> 14;                        // 0 -> pn(t), 1 -> qn(s)
    const int id    = gid & 16383;
    const int n     = id >> 12;
    const int pix   = id & 4095;
    const int y = pix >> 6, x = pix & 63;
    const float* base = (which ? s : t) + n * (C_ * HW_);
    float acc = 0.f;
    for (int c = 0; c < C_; ++c) {
        const float* bc = base + c * HW_;
        #pragma unroll
        for (int dy = 0; dy < 3; ++dy) {
            const float* br = bc + iclamp(y + dy - 1, 0, H_ - 1) * W_;
            #pragma unroll
            for (int dx = 0; dx < 3; ++dx) {
                float v = br[iclamp(x + dx - 1, 0, W_ - 1)];
                acc += v * v;
            }
        }
    }
    (which ? qn : pn)[id] = acc;
}

// ---------------------------------------------------------------------------
// Kernel 2: main cross/argmin over a j-split; partial best -> ws
// thread map: tx = tid&15 -> target group (jrow = tx>>2 of 4 rows,
//             jx0 = (tx&3)*16 of 16 cols);  ty = tid>>4 -> 4 queries i0=ty*4
// ---------------------------------------------------------------------------
__global__ __launch_bounds__(256)
void patchmatch_main_kernel(const float* __restrict__ s,
                            const float* __restrict__ t,
                            const float* __restrict__ pn_g,
                            const float* __restrict__ qn_g,
                            unsigned long long* __restrict__ partial) {
    const int yq    = blockIdx.x;   // query row
    const int n     = blockIdx.y;   // batch
    const int split = blockIdx.z;   // j-split
    const int tid  = threadIdx.x;
    const int tx   = tid & 15;
    const int ty   = tid >> 4;
    const int i0   = ty * 4;          // 4 queries per thread
    const int jrow = tx >> 2;         // target row within 4-row tile
    const int jx0  = (tx & 3) * 16;   // 16 targets per thread

    // padded x: slot xi in [0,65], x = xi-1 (clamped); stride 68 (16B mult)
    __shared__ float qS[C_][3][68];   // 13056 B
    __shared__ float tS[C_][6][68];   // 26112 B
    __shared__ float qnS[W_];         //   256 B   -> total 39424 B, 4 blk/CU

    const float* sb = s + n * (C_ * HW_);
    const float* tb = t + n * (C_ * HW_);

    // ---- stage qS: 48 (c,r) rows x 17 b128 segs, all stores 16B-aligned ----
    for (int id = tid; id < 48 * 17; id += 256) {
        const int row = id / 17;
        const int seg = id - row * 17;
        const int c   = row / 3;
        const int r   = row - c * 3;
        const int gr  = iclamp(yq + r - 1, 0, H_ - 1);
        const float4 v = load_padded_seg(sb + c * HW_ + gr * W_, seg);
        *(float4*)&qS[c][r][4 * seg] = v;
    }
    if (tid < W_) qnS[tid] = qn_g[n * HW_ + yq * W_ + tid];

    unsigned long long best[4] = {~0ull, ~0ull, ~0ull, ~0ull};

    for (int ytl = 0; ytl < TILES_PER_SPLIT; ++ytl) {
        const int yt = split * TILES_PER_SPLIT + ytl;   // 4-row tile id 0..15
        __syncthreads();                   // qS ready (iter 0) / tS reuse
        // ---- stage tS: 96 (c,r) rows x 17 b128 segs ----
        for (int id = tid; id < 96 * 17; id += 256) {
            const int row = id / 17;
            const int seg = id - row * 17;
            const int c   = row / 6;
            const int r   = row - c * 6;
            const int gr  = iclamp(4 * yt + r - 1, 0, H_ - 1);
            const float4 v = load_padded_seg(tb + c * HW_ + gr * W_, seg);
            *(float4*)&tS[c][r][4 * seg] = v;
        }
        __syncthreads();

        float acc[4][16];
        #pragma unroll
        for (int a = 0; a < 4; ++a)
            #pragma unroll
            for (int b = 0; b < 16; ++b) acc[a][b] = 0.f;

        #pragma unroll 1
        for (int c = 0; c < C_; ++c) {
            #pragma unroll
            for (int dy = 0; dy < 3; ++dy) {
                float qv[6], tv[18];
                *(float4*)&qv[0] = *(const float4*)&qS[c][dy][i0];
                *(float2*)&qv[4] = *(const float2*)&qS[c][dy][i0 + 4];
                const float* trow = &tS[c][jrow + dy][jx0];
                *(float4*)&tv[0]  = *(const float4*)&trow[0];
                *(float4*)&tv[4]  = *(const float4*)&trow[4];
                *(float4*)&tv[8]  = *(const float4*)&trow[8];
                *(float4*)&tv[12] = *(const float4*)&trow[12];
                *(float2*)&tv[16] = *(const float2*)&trow[16];
                #pragma unroll
                for (int dx = 0; dx < 3; ++dx)
                    #pragma unroll
                    for (int a = 0; a < 4; ++a)
                        #pragma unroll
                        for (int b = 0; b < 16; ++b)
                            acc[a][b] += qv[a + dx] * tv[b + dx];
            }
        }

        // epilogue: d2 = qn + pn - 2*cross (pn from L2-resident global)
        const int jbase = yt * 256 + jrow * W_ + jx0;   // global j of tv[0]
        float pnv[16];
        const float* png = &pn_g[n * HW_ + jbase];
        *(float4*)&pnv[0]  = *(const float4*)&png[0];
        *(float4*)&pnv[4]  = *(const float4*)&png[4];
        *(float4*)&pnv[8]  = *(const float4*)&png[8];
        *(float4*)&pnv[12] = *(const float4*)&png[12];
        #pragma unroll
        for (int a = 0; a < 4; ++a) {
            const float qn = qnS[i0 + a];
            #pragma unroll
            for (int b = 0; b < 16; ++b) {
                const float d2 = qn + pnv[b] - 2.f * acc[a][b];
                unsigned long long cand =
                    ((unsigned long long)__float_as_uint(d2) << 32) |
                    (unsigned)(jbase + b);
                best[a] = cand < best[a] ? cand : best[a];
            }
        }
    }

    // reduce across the 16 tx lanes sharing each query
    #pragma unroll
    for (int a = 0; a < 4; ++a) {
        unsigned long long v = best[a];
        #pragma unroll
        for (int m = 8; m >= 1; m >>= 1) {
            unsigned long long o = __shfl_xor(v, m, 64);
            v = o < v ? o : v;
        }
        best[a] = v;
    }
    if (tx == 0) {
        #pragma unroll
        for (int a = 0; a < 4; ++a)
            partial[((split * N_ + n) * HW_) + yq * W_ + i0 + a] = best[a];
    }
}

// ---------------------------------------------------------------------------
// Kernel 3: reduce splits, decode, write outputs (as float32)
// ---------------------------------------------------------------------------
__global__ __launch_bounds__(256)
void finalize_kernel(const unsigned long long* __restrict__ partial,
                     float* __restrict__ out) {
    const int id  = blockIdx.x * 256 + threadIdx.x;   // 0..16383
    const int n   = id >> 12;
    const int pix = id & 4095;
    unsigned long long best = ~0ull;
    #pragma unroll
    for (int sp = 0; sp < SPLITS; ++sp) {
        unsigned long long v = partial[(sp * N_ + n) * HW_ + pix];
        best = v < best ? v : best;
    }
    const unsigned j = (unsigned)(best & 0xffffffffu);
    const float d2 = __uint_as_float((unsigned)(best >> 32));
    out[n * 2 * HW_ + pix]            = (float)(j >> 6);  // idy
    out[n * 2 * HW_ + HW_ + pix]      = (float)(j & 63);  // idx_x
    out[N_ * 2 * HW_ + n * HW_ + pix] = d2;               // nnd
}

// ---------------------------------------------------------------------------
// Fallback: monolithic kernel (used only if ws is too small)
// ---------------------------------------------------------------------------
__global__ __launch_bounds__(256)
void patchmatch_mono_kernel(const float* __restrict__ s,
                            const float* __restrict__ t,
                            float* __restrict__ out) {
    const int yq  = blockIdx.x;
    const int n   = blockIdx.y;
    const int tid = threadIdx.x;
    const int tx  = tid & 15;
    const int ty  = tid >> 4;
    const int i0  = ty * 4;
    const int jrow = tx >> 3;
    const int jx0  = (tx & 7) * 8;

    __shared__ float qS[C_][3][68];
    __shared__ float tS[C_][4][68];
    __shared__ float pnS[HW_];
    __shared__ float qnS[W_];

    const float* sb = s + n * (C_ * HW_);
    const float* tb = t + n * (C_ * HW_);

    for (int jj = tid; jj < HW_; jj += 256) {
        const int y = jj >> 6, x = jj & 63;
        float acc = 0.f;
        for (int c = 0; c < C_; ++c) {
            const float* tc = tb + c * HW_;
            #pragma unroll
            for (int dy = 0; dy < 3; ++dy) {
                const float* tr = tc + iclamp(y + dy - 1, 0, H_ - 1) * W_;
                #pragma unroll
                for (int dx = 0; dx < 3; ++dx) {
                    float v = tr[iclamp(x + dx - 1, 0, W_ - 1)];
                    acc += v * v;
                }
            }
        }
        pnS[jj] = acc;
    }
    for (int idx = tid; idx < C_ * 3 * 66; idx += 256) {
        const int c   = idx / (3 * 66);
        const int rem = idx - c * (3 * 66);
        const int rr  = rem / 66;
        const int xi  = rem - rr * 66;
        qS[c][rr][xi] = sb[c * HW_ + iclamp(yq + rr - 1, 0, H_ - 1) * W_ +
                           iclamp(xi - 1, 0, W_ - 1)];
    }
    __syncthreads();
    if (tid < W_) {
        float acc = 0.f;
        for (int c = 0; c < C_; ++c)
            #pragma unroll
            for (int dy = 0; dy < 3; ++dy)
                #pragma unroll
                for (int dx = 0; dx < 3; ++dx) {
                    float v = qS[c][dy][tid + dx];
                    acc += v * v;
                }
        qnS[tid] = acc;
    }

    unsigned long long best[4] = {~0ull, ~0ull, ~0ull, ~0ull};
    for (int yt = 0; yt < 32; ++yt) {
        __syncthreads();
        for (int idx = tid; idx < C_ * 4 * 66; idx += 256) {
            const int c   = idx / (4 * 66);
            const int rem = idx - c * (4 * 66);
            const int rr  = rem / 66;
            const int xi  = rem - rr * 66;
            tS[c][rr][xi] = tb[c * HW_ + iclamp(2 * yt + rr - 1, 0, H_ - 1) * W_ +
                               iclamp(xi - 1, 0, W_ - 1)];
        }
        __syncthreads();

        float acc[4][8];
        #pragma unroll
        for (int a = 0; a < 4; ++a)
            #pragma unroll
            for (int b = 0; b < 8; ++b) acc[a][b] = 0.f;

        #pragma unroll 1
        for (int c = 0; c < C_; ++c) {
            #pragma unroll
            for (int dy = 0; dy < 3; ++dy) {
                float qv[8], tv[12];
                *(float4*)&qv[0] = *(const float4*)&qS[c][dy][i0];
                *(float4*)&qv[4] = *(const float4*)&qS[c][dy][i0 + 4];
                const float* trow = &tS[c][jrow + dy][jx0];
                *(float4*)&tv[0] = *(const float4*)&trow[0];
                *(float4*)&tv[4] = *(const float4*)&trow[4];
                *(float4*)&tv[8] = *(const float4*)&trow[8];
                #pragma unroll
                for (int dx = 0; dx < 3; ++dx)
                    #pragma unroll
                    for (int a = 0; a < 4; ++a)
                        #pragma unroll
                        for (int b = 0; b < 8; ++b)
                            acc[a][b] += qv[a + dx] * tv[b + dx];
            }
        }
        const int rbase = (2 * yt + jrow) * W_ + jx0;
        #pragma unroll
        for (int a = 0; a < 4; ++a) {
            const float qn = qnS[i0 + a];
            #pragma unroll
            for (int b = 0; b < 8; ++b) {
                const int j = rbase + b;
                const float d2 = qn + pnS[j] - 2.f * acc[a][b];
                unsigned long long cand =
                    ((unsigned long long)__float_as_uint(d2) << 32) | (unsigned)j;
                best[a] = cand < best[a] ? cand : best[a];
            }
        }
    }
    #pragma unroll
    for (int a = 0; a < 4; ++a) {
        unsigned long long v = best[a];
        #pragma unroll
        for (int m = 8; m >= 1; m >>= 1) {
            unsigned long long o = __shfl_xor(v, m, 64);
            v = o < v ? o : v;
        }
        best[a] = v;
    }
    if (tx == 0) {
        #pragma unroll
        for (int a = 0; a < 4; ++a) {
            const int x = i0 + a;
            const unsigned j = (unsigned)(best[a] & 0xffffffffu);
            const float d2 = __uint_as_float((unsigned)(best[a] >> 32));
            const int pix = yq * W_ + x;
            out[n * 2 * HW_ + pix]            = (float)(j >> 6);
            out[n * 2 * HW_ + HW_ + pix]      = (float)(j & 63);
            out[N_ * 2 * HW_ + n * HW_ + pix] = d2;
        }
    }
}

extern "C" void kernel_launch(void* const* d_in, const int* in_sizes, int n_in,
                              void* d_out, int out_size, void* d_ws, size_t ws_size,
                              hipStream_t stream) {
    const float* s = (const float*)d_in[0];
    const float* t = (const float*)d_in[1];
    float* out = (float*)d_out;

    // ws layout: pn[4][4096] f32 | qn[4][4096] f32 | partial[4][4][4096] u64
    const size_t need = (size_t)2 * N_ * HW_ * 4 + (size_t)SPLITS * N_ * HW_ * 8;
    if (ws_size < need) {
        dim3 grid(H_, N_);
        patchmatch_mono_kernel<<<grid, 256, 0, stream>>>(s, t, out);
        return;
    }
    float* pn = (float*)d_ws;
    float* qn = pn + N_ * HW_;
    unsigned long long* partial =
        (unsigned long long*)((char*)d_ws + (size_t)2 * N_ * HW_ * 4);

    prep_norms_kernel<<<128, 256, 0, stream>>>(s, t, pn, qn);
    dim3 grid(H_, N_, SPLITS);
    patchmatch_main_kernel<<<grid, 256, 0, stream>>>(s, t, pn, qn, partial);
    finalize_kernel<<<64, 256, 0, stream>>>(partial, out);
}

// Round 6
// 166.484 us; speedup vs baseline: 2.3540x; 2.3540x over previous
//
#include <hip/hip_runtime.h>

// PatchMatch brute-force NN on MI355X.
// s,t (4,16,64,64) fp32; descriptor = 3x3 replicate-padded patch, K=144.
// d2(i,j) = qn_i - 2*cross(i,j) + pn_j; argmin_j (ties -> smallest j).
// Outputs (flat, ALL FLOAT32): nnf (4,2,64,64) then nnd (4,1,64,64).
//
// R6: MFMA path. fp32 -> fp16 hi+lo split (x = hi + lo); cross computed as
// Qh*Ph^T + Qh*Pl^T + Ql*Ph^T with mfma_f32_16x16x32_f16 (error ~2^-22 rel,
// below fp32 reorder noise). Desc arrays (K padded 144->160) materialized
// once into ws; GEMM+argmin kernel keeps A-frags in registers, stages B in
// LDS. Falls back to the R4 fp32 path if ws is too small.

#define N_  4
#define C_  16
#define H_  64
#define W_  64
#define HW_ 4096
#define K_  160              // 144 real + 16 zero-pad
#define SPLITS_M 8           // j-splits for MFMA path
#define JT_PER_SPLIT 8       // j-tiles (64 targets) per split
#define BSTRIDE 168          // LDS B row stride in f16 (336 B, 16B multiple)

#define SPLITS_V 4           // R4 fallback j-splits
#define TILES_PER_SPLIT_V 4

typedef _Float16 f16;
typedef _Float16 f16x8 __attribute__((ext_vector_type(8)));
typedef float    f32x4 __attribute__((ext_vector_type(4)));

__device__ __forceinline__ int iclamp(int v, int lo, int hi) {
    return v < lo ? lo : (v > hi ? hi : v);
}

// ---------------------------------------------------------------------------
// pn[n][4096] from t, qn[n][4096] from s
// ---------------------------------------------------------------------------
__global__ __launch_bounds__(256)
void prep_norms_kernel(const float* __restrict__ s,
                       const float* __restrict__ t,
                       float* __restrict__ pn,
                       float* __restrict__ qn) {
    const int gid   = blockIdx.x * 256 + threadIdx.x;   // 0..32767
    const int which = gid >> 14;                        // 0 -> pn(t), 1 -> qn(s)
    const int id    = gid & 16383;
    const int n     = id >> 12;
    const int pix   = id & 4095;
    const int y = pix >> 6, x = pix & 63;
    const float* base = (which ? s : t) + n * (C_ * HW_);
    float acc = 0.f;
    for (int c = 0; c < C_; ++c) {
        const float* bc = base + c * HW_;
        #pragma unroll
        for (int dy = 0; dy < 3; ++dy) {
            const float* br = bc + iclamp(y + dy - 1, 0, H_ - 1) * W_;
            #pragma unroll
            for (int dx = 0; dx < 3; ++dx) {
                float v = br[iclamp(x + dx - 1, 0, W_ - 1)];
                acc += v * v;
            }
        }
    }
    (which ? qn : pn)[id] = acc;
}

// ---------------------------------------------------------------------------
// Materialize fp16 hi/lo descriptor rows: D[n][pix][k], k = d*16+c (d=dy*3+dx),
// k in [144,160) zero. One thread handles one (pix, 4 k-seg group of 5).
// grid (64, N_, 2): z=0 -> t->Ph/Pl, z=1 -> s->Qh/Ql.
// ---------------------------------------------------------------------------
__global__ __launch_bounds__(256)
void build_desc_kernel(const float* __restrict__ s,
                       const float* __restrict__ t,
                       f16* __restrict__ Qh, f16* __restrict__ Ql,
                       f16* __restrict__ Ph, f16* __restrict__ Pl) {
    const int pix = blockIdx.x * 64 + (threadIdx.x >> 2);
    const int n   = blockIdx.y;
    const int src = blockIdx.z;                 // 0: t, 1: s
    const int y = pix >> 6, x = pix & 63;
    const float* img = (src ? s : t) + n * (C_ * HW_);
    f16* Dh = (src ? Qh : Ph) + (size_t)(n * HW_ + pix) * K_;
    f16* Dl = (src ? Ql : Pl) + (size_t)(n * HW_ + pix) * K_;
    #pragma unroll
    for (int q = 0; q < 5; ++q) {
        const int seg = (threadIdx.x & 3) * 5 + q;   // 0..19
        f16x8 hv, lv;
        if (seg < 18) {
            const int d  = seg >> 1;                 // 0..8
            const int c0 = (seg & 1) * 8;
            const int dy = (d >= 6) ? 2 : (d >= 3 ? 1 : 0);
            const int dx = d - dy * 3;
            const int ys = iclamp(y + dy - 1, 0, H_ - 1);
            const int xs = iclamp(x + dx - 1, 0, W_ - 1);
            const float* p0 = img + c0 * HW_ + ys * W_ + xs;
            #pragma unroll
            for (int cc = 0; cc < 8; ++cc) {
                const float v = p0[cc * HW_];
                const f16 h = (f16)v;
                hv[cc] = h;
                lv[cc] = (f16)(v - (float)h);
            }
        } else {
            #pragma unroll
            for (int cc = 0; cc < 8; ++cc) { hv[cc] = (f16)0.f; lv[cc] = (f16)0.f; }
        }
        *(f16x8*)&Dh[seg * 8] = hv;
        *(f16x8*)&Dl[seg * 8] = lv;
    }
}

// ---------------------------------------------------------------------------
// MFMA GEMM + fused argmin over a j-split.
// Block: 256 thr = 4 waves; block i-tile = 128 (wave: 32i), j streamed in
// 64-target tiles. A-frags (Qh,Ql) register-resident; B (Ph,Pl) via LDS.
// mfma_f32_16x16x32_f16: A[m=lane&15][k=quad*8+e]; C: col=lane&15,
// row=quad*4+reg (m89-verified layouts).
// ---------------------------------------------------------------------------
__global__ __launch_bounds__(256)
void mfma_nn_kernel(const f16* __restrict__ Qh, const f16* __restrict__ Ql,
                    const f16* __restrict__ Ph, const f16* __restrict__ Pl,
                    const float* __restrict__ pn_g,
                    unsigned long long* __restrict__ partial) {
    const int iblk = blockIdx.x, n = blockIdx.y, split = blockIdx.z;
    const int tid  = threadIdx.x;
    const int wave = tid >> 6, lane = tid & 63;
    const int m = lane & 15, quad = lane >> 4;

    __shared__ f16 Bh[64 * BSTRIDE];   // 21504 B
    __shared__ f16 Bl[64 * BSTRIDE];   // 21504 B

    // ---- A fragments, loaded once ----
    const int irow0 = iblk * 128 + wave * 32;
    f16x8 Ah[2][5], Al[2][5];
    #pragma unroll
    for (int is = 0; is < 2; ++is)
        #pragma unroll
        for (int kc = 0; kc < 5; ++kc) {
            const size_t off =
                (size_t)(n * HW_ + irow0 + is * 16 + m) * K_ + kc * 32 + quad * 8;
            Ah[is][kc] = *(const f16x8*)(Qh + off);
            Al[is][kc] = *(const f16x8*)(Ql + off);
        }

    float    bd[2][4];
    unsigned bj[2][4];
    #pragma unroll
    for (int is = 0; is < 2; ++is)
        #pragma unroll
        for (int rg = 0; rg < 4; ++rg) { bd[is][rg] = 3.0e38f; bj[is][rg] = 0u; }

    const int rstage = tid >> 2;          // staging row 0..63
    const int sbase  = (tid & 3) * 5;     // 5 segs per thread

    for (int jt = 0; jt < JT_PER_SPLIT; ++jt) {
        const int j0 = split * 512 + jt * 64;
        __syncthreads();
        #pragma unroll
        for (int q = 0; q < 5; ++q) {
            const int seg = sbase + q;
            const size_t goff = (size_t)(n * HW_ + j0 + rstage) * K_ + seg * 8;
            *(f16x8*)&Bh[rstage * BSTRIDE + seg * 8] = *(const f16x8*)(Ph + goff);
            *(f16x8*)&Bl[rstage * BSTRIDE + seg * 8] = *(const f16x8*)(Pl + goff);
        }
        __syncthreads();

        float pnv[4];
        #pragma unroll
        for (int js = 0; js < 4; ++js)
            pnv[js] = pn_g[n * HW_ + j0 + js * 16 + m];

        f32x4 Cf[2][4];
        #pragma unroll
        for (int is = 0; is < 2; ++is)
            #pragma unroll
            for (int js = 0; js < 4; ++js) Cf[is][js] = (f32x4){0.f, 0.f, 0.f, 0.f};

        #pragma unroll
        for (int kc = 0; kc < 5; ++kc) {
            #pragma unroll
            for (int js = 0; js < 4; ++js) {
                const int boff = (js * 16 + m) * BSTRIDE + kc * 32 + quad * 8;
                const f16x8 bh = *(const f16x8*)&Bh[boff];
                const f16x8 bl = *(const f16x8*)&Bl[boff];
                #pragma unroll
                for (int is = 0; is < 2; ++is) {
                    Cf[is][js] = __builtin_amdgcn_mfma_f32_16x16x32_f16(
                        Ah[is][kc], bh, Cf[is][js], 0, 0, 0);
                    Cf[is][js] = __builtin_amdgcn_mfma_f32_16x16x32_f16(
                        Al[is][kc], bh, Cf[is][js], 0, 0, 0);
                    Cf[is][js] = __builtin_amdgcn_mfma_f32_16x16x32_f16(
                        Ah[is][kc], bl, Cf[is][js], 0, 0, 0);
                }
            }
        }

        // ---- epilogue: argmin of d' = pn - 2*cross (qn added in finalize) ----
        #pragma unroll
        for (int is = 0; is < 2; ++is)
            #pragma unroll
            for (int rg = 0; rg < 4; ++rg) {
                const float d0 = fmaf(Cf[is][0][rg], -2.f, pnv[0]);
                const float d1 = fmaf(Cf[is][1][rg], -2.f, pnv[1]);
                const float d2 = fmaf(Cf[is][2][rg], -2.f, pnv[2]);
                const float d3 = fmaf(Cf[is][3][rg], -2.f, pnv[3]);
                const int   sA = (d1 < d0) ? 1 : 0;  const float dA = fminf(d0, d1);
                const int   sB = (d3 < d2) ? 3 : 2;  const float dB = fminf(d2, d3);
                const int   sm = (dB < dA) ? sB : sA; const float dm = fminf(dA, dB);
                if (dm < bd[is][rg]) {
                    bd[is][rg] = dm;
                    bj[is][rg] = (unsigned)(jt * 64 + sm * 16 + m);
                }
            }
    }

    // ---- reduce across the 16 m-lanes (same quad holds same i rows) ----
    #pragma unroll
    for (int is = 0; is < 2; ++is)
        #pragma unroll
        for (int rg = 0; rg < 4; ++rg) {
            float    d = bd[is][rg];
            unsigned j = (unsigned)(split * 512) + bj[is][rg];   // global j
            #pragma unroll
            for (int off = 1; off < 16; off <<= 1) {
                const float    od = __shfl_xor(d, off, 64);
                const unsigned oj = __shfl_xor(j, off, 64);
                const bool take = (od < d) || (od == d && oj < j);
                d = take ? od : d;
                j = take ? oj : j;
            }
            if (m == 0) {
                const int i = irow0 + is * 16 + quad * 4 + rg;
                partial[(size_t)(split * N_ + n) * HW_ + i] =
                    ((unsigned long long)j << 32) |
                    (unsigned long long)__float_as_uint(d);
            }
        }
}

// ---------------------------------------------------------------------------
// Reduce splits, add qn, decode, write outputs (float32)
// ---------------------------------------------------------------------------
__global__ __launch_bounds__(256)
void finalize_mfma_kernel(const unsigned long long* __restrict__ partial,
                          const float* __restrict__ qn_g,
                          float* __restrict__ out) {
    const int id  = blockIdx.x * 256 + threadIdx.x;   // 0..16383
    const int n   = id >> 12;
    const int pix = id & 4095;
    float    bd = 3.0e38f;
    unsigned bj = 0u;
    #pragma unroll
    for (int sp = 0; sp < SPLITS_M; ++sp) {
        const unsigned long long v = partial[(size_t)(sp * N_ + n) * HW_ + pix];
        const float    d = __uint_as_float((unsigned)(v & 0xffffffffull));
        const unsigned j = (unsigned)(v >> 32);
        const bool take = (d < bd) || (d == bd && j < bj);
        bd = take ? d : bd;
        bj = take ? j : bj;
    }
    out[n * 2 * HW_ + pix]            = (float)(bj >> 6);          // idy
    out[n * 2 * HW_ + HW_ + pix]      = (float)(bj & 63);          // idx_x
    out[N_ * 2 * HW_ + n * HW_ + pix] = bd + qn_g[n * HW_ + pix];  // nnd
}

// ===========================================================================
// Fallback 1: R4 fp32 vector path (prep_norms + main + finalize)
// ===========================================================================
__global__ __launch_bounds__(256)
void patchmatch_main_kernel(const float* __restrict__ s,
                            const float* __restrict__ t,
                            const float* __restrict__ pn_g,
                            const float* __restrict__ qn_g,
                            unsigned long long* __restrict__ partial) {
    const int yq    = blockIdx.x;
    const int n     = blockIdx.y;
    const int split = blockIdx.z;
    const int tid  = threadIdx.x;
    const int tx   = tid & 15;
    const int ty   = tid >> 4;
    const int i0   = ty * 4;
    const int jrow = tx >> 2;
    const int jx0  = (tx & 3) * 16;

    __shared__ float qS[C_][3][68];
    __shared__ float tS[C_][6][68];
    __shared__ float qnS[W_];

    const float* sb = s + n * (C_ * HW_);
    const float* tb = t + n * (C_ * HW_);

    #pragma unroll
    for (int k = 0; k < 3; ++k) {
        const int id = tid + k * 256;
        const int sg = id & 15;
        const int c  = (id >> 4) & 15;
        const int r  = id >> 8;
        const int gr = iclamp(yq + r - 1, 0, H_ - 1);
        const float4 v = *(const float4*)&sb[c * HW_ + gr * W_ + sg * 4];
        float* dst = &qS[c][r][1 + sg * 4];
        dst[0] = v.x; dst[1] = v.y; dst[2] = v.z; dst[3] = v.w;
    }
    if (tid < 48) {
        const int c  = tid & 15;
        const int r  = tid >> 4;
        const int gr = iclamp(yq + r - 1, 0, H_ - 1);
        qS[c][r][0]  = sb[c * HW_ + gr * W_];
        qS[c][r][65] = sb[c * HW_ + gr * W_ + 63];
    }
    if (tid < W_) qnS[tid] = qn_g[n * HW_ + yq * W_ + tid];

    unsigned long long best[4] = {~0ull, ~0ull, ~0ull, ~0ull};

    for (int ytl = 0; ytl < TILES_PER_SPLIT_V; ++ytl) {
        const int yt = split * TILES_PER_SPLIT_V + ytl;
        __syncthreads();
        #pragma unroll
        for (int k = 0; k < 6; ++k) {
            const int id = tid + k * 256;
            const int sg = id & 15;
            const int c  = (id >> 4) & 15;
            const int r  = id >> 8;
            const int gr = iclamp(4 * yt + r - 1, 0, H_ - 1);
            const float4 v = *(const float4*)&tb[c * HW_ + gr * W_ + sg * 4];
            float* dst = &tS[c][r][1 + sg * 4];
            dst[0] = v.x; dst[1] = v.y; dst[2] = v.z; dst[3] = v.w;
        }
        if (tid < 96) {
            const int c  = tid & 15;
            const int r  = tid >> 4;
            const int gr = iclamp(4 * yt + r - 1, 0, H_ - 1);
            tS[c][r][0]  = tb[c * HW_ + gr * W_];
            tS[c][r][65] = tb[c * HW_ + gr * W_ + 63];
        }
        __syncthreads();

        float acc[4][16];
        #pragma unroll
        for (int a = 0; a < 4; ++a)
            #pragma unroll
            for (int b = 0; b < 16; ++b) acc[a][b] = 0.f;

        for (int c = 0; c < C_; ++c) {
            #pragma unroll
            for (int dy = 0; dy < 3; ++dy) {
                float qv[6], tv[18];
                *(float4*)&qv[0] = *(const float4*)&qS[c][dy][i0];
                *(float2*)&qv[4] = *(const float2*)&qS[c][dy][i0 + 4];
                const float* trow = &tS[c][jrow + dy][jx0];
                *(float4*)&tv[0]  = *(const float4*)&trow[0];
                *(float4*)&tv[4]  = *(const float4*)&trow[4];
                *(float4*)&tv[8]  = *(const float4*)&trow[8];
                *(float4*)&tv[12] = *(const float4*)&trow[12];
                *(float2*)&tv[16] = *(const float2*)&trow[16];
                #pragma unroll
                for (int dx = 0; dx < 3; ++dx)
                    #pragma unroll
                    for (int a = 0; a < 4; ++a)
                        #pragma unroll
                        for (int b = 0; b < 16; ++b)
                            acc[a][b] += qv[a + dx] * tv[b + dx];
            }
        }

        const int jbase = yt * 256 + jrow * W_ + jx0;
        float pnv[16];
        const float* png = &pn_g[n * HW_ + jbase];
        *(float4*)&pnv[0]  = *(const float4*)&png[0];
        *(float4*)&pnv[4]  = *(const float4*)&png[4];
        *(float4*)&pnv[8]  = *(const float4*)&png[8];
        *(float4*)&pnv[12] = *(const float4*)&png[12];
        #pragma unroll
        for (int a = 0; a < 4; ++a) {
            const float qn = qnS[i0 + a];
            #pragma unroll
            for (int b = 0; b < 16; ++b) {
                const float d2 = qn + pnv[b] - 2.f * acc[a][b];
                unsigned long long cand =
                    ((unsigned long long)__float_as_uint(d2) << 32) |
                    (unsigned)(jbase + b);
                best[a] = cand < best[a] ? cand : best[a];
            }
        }
    }

    #pragma unroll
    for (int a = 0; a < 4; ++a) {
        unsigned long long v = best[a];
        #pragma unroll
        for (int mm = 8; mm >= 1; mm >>= 1) {
            unsigned long long o = __shfl_xor(v, mm, 64);
            v = o < v ? o : v;
        }
        best[a] = v;
    }
    if (tx == 0) {
        #pragma unroll
        for (int a = 0; a < 4; ++a)
            partial[((split * N_ + n) * HW_) + yq * W_ + i0 + a] = best[a];
    }
}

__global__ __launch_bounds__(256)
void finalize_kernel(const unsigned long long* __restrict__ partial,
                     float* __restrict__ out) {
    const int id  = blockIdx.x * 256 + threadIdx.x;
    const int n   = id >> 12;
    const int pix = id & 4095;
    unsigned long long best = ~0ull;
    #pragma unroll
    for (int sp = 0; sp < SPLITS_V; ++sp) {
        unsigned long long v = partial[(sp * N_ + n) * HW_ + pix];
        best = v < best ? v : best;
    }
    const unsigned j = (unsigned)(best & 0xffffffffu);
    const float d2 = __uint_as_float((unsigned)(best >> 32));
    out[n * 2 * HW_ + pix]            = (float)(j >> 6);
    out[n * 2 * HW_ + HW_ + pix]      = (float)(j & 63);
    out[N_ * 2 * HW_ + n * HW_ + pix] = d2;
}

// ===========================================================================
// Fallback 2: monolithic kernel (no workspace at all)
// ===========================================================================
__global__ __launch_bounds__(256)
void patchmatch_mono_kernel(const float* __restrict__ s,
                            const float* __restrict__ t,
                            float* __restrict__ out) {
    const int yq  = blockIdx.x;
    const int n   = blockIdx.y;
    const int tid = threadIdx.x;
    const int tx  = tid & 15;
    const int ty  = tid >> 4;
    const int i0  = ty * 4;
    const int jrow = tx >> 3;
    const int jx0  = (tx & 7) * 8;

    __shared__ float qS[C_][3][68];
    __shared__ float tS[C_][4][68];
    __shared__ float pnS[HW_];
    __shared__ float qnS[W_];

    const float* sb = s + n * (C_ * HW_);
    const float* tb = t + n * (C_ * HW_);

    for (int jj = tid; jj < HW_; jj += 256) {
        const int y = jj >> 6, x = jj & 63;
        float acc = 0.f;
        for (int c = 0; c < C_; ++c) {
            const float* tc = tb + c * HW_;
            #pragma unroll
            for (int dy = 0; dy < 3; ++dy) {
                const float* tr = tc + iclamp(y + dy - 1, 0, H_ - 1) * W_;
                #pragma unroll
                for (int dx = 0; dx < 3; ++dx) {
                    float v = tr[iclamp(x + dx - 1, 0, W_ - 1)];
                    acc += v * v;
                }
            }
        }
        pnS[jj] = acc;
    }
    for (int idx = tid; idx < C_ * 3 * 66; idx += 256) {
        const int c   = idx / (3 * 66);
        const int rem = idx - c * (3 * 66);
        const int rr  = rem / 66;
        const int xi  = rem - rr * 66;
        qS[c][rr][xi] = sb[c * HW_ + iclamp(yq + rr - 1, 0, H_ - 1) * W_ +
                           iclamp(xi - 1, 0, W_ - 1)];
    }
    __syncthreads();
    if (tid < W_) {
        float acc = 0.f;
        for (int c = 0; c < C_; ++c)
            #pragma unroll
            for (int dy = 0; dy < 3; ++dy)
                #pragma unroll
                for (int dx = 0; dx < 3; ++dx) {
                    float v = qS[c][dy][tid + dx];
                    acc += v * v;
                }
        qnS[tid] = acc;
    }

    unsigned long long best[4] = {~0ull, ~0ull, ~0ull, ~0ull};
    for (int yt = 0; yt < 32; ++yt) {
        __syncthreads();
        for (int idx = tid; idx < C_ * 4 * 66; idx += 256) {
            const int c   = idx / (4 * 66);
            const int rem = idx - c * (4 * 66);
            const int rr  = rem / 66;
            const int xi  = rem - rr * 66;
            tS[c][rr][xi] = tb[c * HW_ + iclamp(2 * yt + rr - 1, 0, H_ - 1) * W_ +
                               iclamp(xi - 1, 0, W_ - 1)];
        }
        __syncthreads();

        float acc[4][8];
        #pragma unroll
        for (int a = 0; a < 4; ++a)
            #pragma unroll
            for (int b = 0; b < 8; ++b) acc[a][b] = 0.f;

        for (int c = 0; c < C_; ++c) {
            #pragma unroll
            for (int dy = 0; dy < 3; ++dy) {
                float qv[8], tv[12];
                *(float4*)&qv[0] = *(const float4*)&qS[c][dy][i0];
                *(float4*)&qv[4] = *(const float4*)&qS[c][dy][i0 + 4];
                const float* trow = &tS[c][jrow + dy][jx0];
                *(float4*)&tv[0] = *(const float4*)&trow[0];
                *(float4*)&tv[4] = *(const float4*)&trow[4];
                *(float4*)&tv[8] = *(const float4*)&trow[8];
                #pragma unroll
                for (int dx = 0; dx < 3; ++dx)
                    #pragma unroll
                    for (int a = 0; a < 4; ++a)
                        #pragma unroll
                        for (int b = 0; b < 8; ++b)
                            acc[a][b] += qv[a + dx] * tv[b + dx];
            }
        }
        const int rbase = (2 * yt + jrow) * W_ + jx0;
        #pragma unroll
        for (int a = 0; a < 4; ++a) {
            const float qn = qnS[i0 + a];
            #pragma unroll
            for (int b = 0; b < 8; ++b) {
                const int j = rbase + b;
                const float d2 = qn + pnS[j] - 2.f * acc[a][b];
                unsigned long long cand =
                    ((unsigned long long)__float_as_uint(d2) << 32) | (unsigned)j;
                best[a] = cand < best[a] ? cand : best[a];
            }
        }
    }
    #pragma unroll
    for (int a = 0; a < 4; ++a) {
        unsigned long long v = best[a];
        #pragma unroll
        for (int mm = 8; mm >= 1; mm >>= 1) {
            unsigned long long o = __shfl_xor(v, mm, 64);
            v = o < v ? o : v;
        }
        best[a] = v;
    }
    if (tx == 0) {
        #pragma unroll
        for (int a = 0; a < 4; ++a) {
            const int x = i0 + a;
            const unsigned j = (unsigned)(best[a] & 0xffffffffu);
            const float d2 = __uint_as_float((unsigned)(best[a] >> 32));
            const int pix = yq * W_ + x;
            out[n * 2 * HW_ + pix]            = (float)(j >> 6);
            out[n * 2 * HW_ + HW_ + pix]      = (float)(j & 63);
            out[N_ * 2 * HW_ + n * HW_ + pix] = d2;
        }
    }
}

// ===========================================================================
extern "C" void kernel_launch(void* const* d_in, const int* in_sizes, int n_in,
                              void* d_out, int out_size, void* d_ws, size_t ws_size,
                              hipStream_t stream) {
    const float* s = (const float*)d_in[0];
    const float* t = (const float*)d_in[1];
    float* out = (float*)d_out;

    // MFMA ws layout:
    //   pn [4][4096] f32 | qn [4][4096] f32 | partial [8][4][4096] u64 |
    //   Qh | Ql | Ph | Pl   each [4][4096][160] f16
    const size_t norm_b  = (size_t)N_ * HW_ * 4;                 // 64 KB each
    const size_t part_b  = (size_t)SPLITS_M * N_ * HW_ * 8;      // 1 MB
    const size_t desc_b  = (size_t)N_ * HW_ * K_ * 2;            // 5.24 MB each
    const size_t need_m  = 2 * norm_b + part_b + 4 * desc_b;     // ~22 MB

    if (ws_size >= need_m) {
        char* w = (char*)d_ws;
        float* pn = (float*)w;                       w += norm_b;
        float* qn = (float*)w;                       w += norm_b;
        unsigned long long* partial = (unsigned long long*)w; w += part_b;
        f16* Qh = (f16*)w;  w += desc_b;
        f16* Ql = (f16*)w;  w += desc_b;
        f16* Ph = (f16*)w;  w += desc_b;
        f16* Pl = (f16*)w;

        prep_norms_kernel<<<128, 256, 0, stream>>>(s, t, pn, qn);
        build_desc_kernel<<<dim3(64, N_, 2), 256, 0, stream>>>(s, t, Qh, Ql, Ph, Pl);
        mfma_nn_kernel<<<dim3(32, N_, SPLITS_M), 256, 0, stream>>>(
            Qh, Ql, Ph, Pl, pn, partial);
        finalize_mfma_kernel<<<64, 256, 0, stream>>>(partial, qn, out);
        return;
    }

    // Fallback: R4 fp32 path
    const size_t need_v = 2 * norm_b + (size_t)SPLITS_V * N_ * HW_ * 8;
    if (ws_size >= need_v) {
        float* pn = (float*)d_ws;
        float* qn = pn + N_ * HW_;
        unsigned long long* partial =
            (unsigned long long*)((char*)d_ws + 2 * norm_b);
        prep_norms_kernel<<<128, 256, 0, stream>>>(s, t, pn, qn);
        dim3 grid(H_, N_, SPLITS_V);
        patchmatch_main_kernel<<<grid, 256, 0, stream>>>(s, t, pn, qn, partial);
        finalize_kernel<<<64, 256, 0, stream>>>(partial, out);
        return;
    }

    dim3 grid(H_, N_);
    patchmatch_mono_kernel<<<grid, 256, 0, stream>>>(s, t, out);
}

// Round 7
// 158.341 us; speedup vs baseline: 2.4751x; 1.0514x over previous
//
#include <hip/hip_runtime.h>

// PatchMatch brute-force NN on MI355X.
// s,t (4,16,64,64) fp32; descriptor = 3x3 replicate-padded patch, K=144.
// d2(i,j) = qn_i - 2*cross(i,j) + pn_j; argmin_j (ties -> smallest j).
// Outputs (flat, ALL FLOAT32): nnf (4,2,64,64) then nnd (4,1,64,64).
//
// R7 vs R6 (166us total, mfma kernel 99us, MfmaUtil 27%, occupancy 21%):
//  - j-tile 64->32: LDS 43KB->21.9KB so ~5 blocks/CU fit (grid 4/CU fully
//    resident; barrier stalls overlap across blocks).
//  - B-row bank swizzle (+64B per 8 rows): breaks the exact m<->m+8 bank
//    collision of the 336B stride (336*8 === 0 mod 128).
//  - prep_norms fused into build_desc (4-thread/pix shuffle reduction).

#define N_  4
#define C_  16
#define H_  64
#define W_  64
#define HW_ 4096
#define K_  160              // 144 real + 16 zero-pad
#define SPLITS_M 8           // j-splits for MFMA path
#define JT_PER_SPLIT 16      // j-tiles (32 targets) per split
#define BROW 168             // base B row stride in f16 (336 B)

#define SPLITS_V 4           // fallback j-splits
#define TILES_PER_SPLIT_V 4

typedef _Float16 f16;
typedef _Float16 f16x8 __attribute__((ext_vector_type(8)));
typedef float    f32x4 __attribute__((ext_vector_type(4)));

__device__ __forceinline__ int iclamp(int v, int lo, int hi) {
    return v < lo ? lo : (v > hi ? hi : v);
}
// swizzled B row start (f16 units): +32 f16 (64 B) every 8 rows
__device__ __forceinline__ int brow_start(int j) {
    return j * BROW + (j >> 3) * 32;
}

// ---------------------------------------------------------------------------
// Kernel 1: build fp16 hi/lo descriptors AND the squared norms.
// D[n][pix][k], k = d*16+c (d=dy*3+dx); k in [144,160) zero.
// grid (64, N_, 2): z=0 -> t->Ph/Pl + pn, z=1 -> s->Qh/Ql + qn.
// 4 threads per pix, 5 k-segs (of 8) each.
// ---------------------------------------------------------------------------
__global__ __launch_bounds__(256)
void build_desc_norms_kernel(const float* __restrict__ s,
                             const float* __restrict__ t,
                             f16* __restrict__ Qh, f16* __restrict__ Ql,
                             f16* __restrict__ Ph, f16* __restrict__ Pl,
                             float* __restrict__ pn,
                             float* __restrict__ qn) {
    const int pix = blockIdx.x * 64 + (threadIdx.x >> 2);
    const int n   = blockIdx.y;
    const int src = blockIdx.z;                 // 0: t, 1: s
    const int y = pix >> 6, x = pix & 63;
    const float* img = (src ? s : t) + n * (C_ * HW_);
    f16* Dh = (src ? Qh : Ph) + (size_t)(n * HW_ + pix) * K_;
    f16* Dl = (src ? Ql : Pl) + (size_t)(n * HW_ + pix) * K_;
    float nacc = 0.f;
    #pragma unroll
    for (int q = 0; q < 5; ++q) {
        const int seg = (threadIdx.x & 3) * 5 + q;   // 0..19
        f16x8 hv, lv;
        if (seg < 18) {
            const int d  = seg >> 1;                 // 0..8
            const int c0 = (seg & 1) * 8;
            const int dy = (d >= 6) ? 2 : (d >= 3 ? 1 : 0);
            const int dx = d - dy * 3;
            const int ys = iclamp(y + dy - 1, 0, H_ - 1);
            const int xs = iclamp(x + dx - 1, 0, W_ - 1);
            const float* p0 = img + c0 * HW_ + ys * W_ + xs;
            #pragma unroll
            for (int cc = 0; cc < 8; ++cc) {
                const float v = p0[cc * HW_];
                const f16 h = (f16)v;
                hv[cc] = h;
                lv[cc] = (f16)(v - (float)h);
                nacc += v * v;
            }
        } else {
            #pragma unroll
            for (int cc = 0; cc < 8; ++cc) { hv[cc] = (f16)0.f; lv[cc] = (f16)0.f; }
        }
        *(f16x8*)&Dh[seg * 8] = hv;
        *(f16x8*)&Dl[seg * 8] = lv;
    }
    // reduce norm across the 4 threads of this pix (adjacent lanes)
    nacc += __shfl_xor(nacc, 1, 64);
    nacc += __shfl_xor(nacc, 2, 64);
    if ((threadIdx.x & 3) == 0)
        (src ? qn : pn)[n * HW_ + pix] = nacc;
}

// ---------------------------------------------------------------------------
// Kernel 2: MFMA GEMM + fused argmin over a j-split.
// Block: 256 thr = 4 waves; block i-tile 128 (wave: 32i = 2x16), j streamed
// in 32-target tiles. A-frags register-resident; B via swizzled LDS.
// mfma_f32_16x16x32_f16: A[m=lane&15][k=quad*8+e]; C: col=lane&15,
// row=quad*4+reg.
// ---------------------------------------------------------------------------
__global__ __launch_bounds__(256)
void mfma_nn_kernel(const f16* __restrict__ Qh, const f16* __restrict__ Ql,
                    const f16* __restrict__ Ph, const f16* __restrict__ Pl,
                    const float* __restrict__ pn_g,
                    unsigned long long* __restrict__ partial) {
    const int iblk = blockIdx.x, n = blockIdx.y, split = blockIdx.z;
    const int tid  = threadIdx.x;
    const int wave = tid >> 6, lane = tid & 63;
    const int m = lane & 15, quad = lane >> 4;

    // 32 rows, swizzled: size = brow_start(32) = 32*168+128 = 5504 f16
    __shared__ f16 BhS[5504];   // 11008 B
    __shared__ f16 BlS[5504];   // 11008 B  -> 22016 B total

    // ---- A fragments, loaded once ----
    const int irow0 = iblk * 128 + wave * 32;
    f16x8 Ah[2][5], Al[2][5];
    #pragma unroll
    for (int is = 0; is < 2; ++is)
        #pragma unroll
        for (int kc = 0; kc < 5; ++kc) {
            const size_t off =
                (size_t)(n * HW_ + irow0 + is * 16 + m) * K_ + kc * 32 + quad * 8;
            Ah[is][kc] = *(const f16x8*)(Qh + off);
            Al[is][kc] = *(const f16x8*)(Ql + off);
        }

    float    bd[2][4];
    unsigned bj[2][4];
    #pragma unroll
    for (int is = 0; is < 2; ++is)
        #pragma unroll
        for (int rg = 0; rg < 4; ++rg) { bd[is][rg] = 3.0e38f; bj[is][rg] = 0u; }

    for (int jt = 0; jt < JT_PER_SPLIT; ++jt) {
        const int j0 = split * 512 + jt * 32;
        __syncthreads();                 // protect prior-tile readers
        // ---- stage 32 rows x 20 segs x {hi,lo}: 1280 chunks, 5/thread ----
        #pragma unroll
        for (int k = 0; k < 5; ++k) {
            const int id  = tid + k * 256;        // 0..1279
            const int arr = (id >= 640);
            const int rid = id - arr * 640;
            const int row = rid / 20;
            const int seg = rid - row * 20;
            const size_t goff = (size_t)(n * HW_ + j0 + row) * K_ + seg * 8;
            const int    loff = brow_start(row) + seg * 8;
            if (arr) *(f16x8*)&BlS[loff] = *(const f16x8*)(Pl + goff);
            else     *(f16x8*)&BhS[loff] = *(const f16x8*)(Ph + goff);
        }
        __syncthreads();

        float pnv[2];
        #pragma unroll
        for (int js = 0; js < 2; ++js)
            pnv[js] = pn_g[n * HW_ + j0 + js * 16 + m];

        f32x4 Cf[2][2];
        #pragma unroll
        for (int is = 0; is < 2; ++is)
            #pragma unroll
            for (int js = 0; js < 2; ++js) Cf[is][js] = (f32x4){0.f, 0.f, 0.f, 0.f};

        #pragma unroll
        for (int kc = 0; kc < 5; ++kc) {
            #pragma unroll
            for (int js = 0; js < 2; ++js) {
                const int boff = brow_start(js * 16 + m) + kc * 32 + quad * 8;
                const f16x8 bh = *(const f16x8*)&BhS[boff];
                const f16x8 bl = *(const f16x8*)&BlS[boff];
                #pragma unroll
                for (int is = 0; is < 2; ++is) {
                    Cf[is][js] = __builtin_amdgcn_mfma_f32_16x16x32_f16(
                        Ah[is][kc], bh, Cf[is][js], 0, 0, 0);
                    Cf[is][js] = __builtin_amdgcn_mfma_f32_16x16x32_f16(
                        Al[is][kc], bh, Cf[is][js], 0, 0, 0);
                    Cf[is][js] = __builtin_amdgcn_mfma_f32_16x16x32_f16(
                        Ah[is][kc], bl, Cf[is][js], 0, 0, 0);
                }
            }
        }

        // ---- epilogue: argmin of d' = pn - 2*cross (qn added in finalize) ----
        #pragma unroll
        for (int is = 0; is < 2; ++is)
            #pragma unroll
            for (int rg = 0; rg < 4; ++rg) {
                const float d0 = fmaf(Cf[is][0][rg], -2.f, pnv[0]);
                const float d1 = fmaf(Cf[is][1][rg], -2.f, pnv[1]);
                const int   sm = (d1 < d0) ? 1 : 0;
                const float dm = fminf(d0, d1);
                if (dm < bd[is][rg]) {
                    bd[is][rg] = dm;
                    bj[is][rg] = (unsigned)(jt * 32 + sm * 16 + m);
                }
            }
    }

    // ---- reduce across the 16 m-lanes ----
    #pragma unroll
    for (int is = 0; is < 2; ++is)
        #pragma unroll
        for (int rg = 0; rg < 4; ++rg) {
            float    d = bd[is][rg];
            unsigned j = (unsigned)(split * 512) + bj[is][rg];   // global j
            #pragma unroll
            for (int off = 1; off < 16; off <<= 1) {
                const float    od = __shfl_xor(d, off, 64);
                const unsigned oj = __shfl_xor(j, off, 64);
                const bool take = (od < d) || (od == d && oj < j);
                d = take ? od : d;
                j = take ? oj : j;
            }
            if (m == 0) {
                const int i = irow0 + is * 16 + quad * 4 + rg;
                partial[(size_t)(split * N_ + n) * HW_ + i] =
                    ((unsigned long long)j << 32) |
                    (unsigned long long)__float_as_uint(d);
            }
        }
}

// ---------------------------------------------------------------------------
// Kernel 3: reduce splits, add qn, decode, write outputs (float32)
// ---------------------------------------------------------------------------
__global__ __launch_bounds__(256)
void finalize_mfma_kernel(const unsigned long long* __restrict__ partial,
                          const float* __restrict__ qn_g,
                          float* __restrict__ out) {
    const int id  = blockIdx.x * 256 + threadIdx.x;   // 0..16383
    const int n   = id >> 12;
    const int pix = id & 4095;
    float    bd = 3.0e38f;
    unsigned bj = 0u;
    #pragma unroll
    for (int sp = 0; sp < SPLITS_M; ++sp) {
        const unsigned long long v = partial[(size_t)(sp * N_ + n) * HW_ + pix];
        const float    d = __uint_as_float((unsigned)(v & 0xffffffffull));
        const unsigned j = (unsigned)(v >> 32);
        const bool take = (d < bd) || (d == bd && j < bj);
        bd = take ? d : bd;
        bj = take ? j : bj;
    }
    out[n * 2 * HW_ + pix]            = (float)(bj >> 6);          // idy
    out[n * 2 * HW_ + HW_ + pix]      = (float)(bj & 63);          // idx_x
    out[N_ * 2 * HW_ + n * HW_ + pix] = bd + qn_g[n * HW_ + pix];  // nnd
}

// ===========================================================================
// Fallback path (fp32 vector, R4 structure) + helpers
// ===========================================================================
__global__ __launch_bounds__(256)
void prep_norms_kernel(const float* __restrict__ s,
                       const float* __restrict__ t,
                       float* __restrict__ pn,
                       float* __restrict__ qn) {
    const int gid   = blockIdx.x * 256 + threadIdx.x;
    const int which = gid >> 14;
    const int id    = gid & 16383;
    const int n     = id >> 12;
    const int pix   = id & 4095;
    const int y = pix >> 6, x = pix & 63;
    const float* base = (which ? s : t) + n * (C_ * HW_);
    float acc = 0.f;
    for (int c = 0; c < C_; ++c) {
        const float* bc = base + c * HW_;
        #pragma unroll
        for (int dy = 0; dy < 3; ++dy) {
            const float* br = bc + iclamp(y + dy - 1, 0, H_ - 1) * W_;
            #pragma unroll
            for (int dx = 0; dx < 3; ++dx) {
                float v = br[iclamp(x + dx - 1, 0, W_ - 1)];
                acc += v * v;
            }
        }
    }
    (which ? qn : pn)[id] = acc;
}

__global__ __launch_bounds__(256)
void patchmatch_main_kernel(const float* __restrict__ s,
                            const float* __restrict__ t,
                            const float* __restrict__ pn_g,
                            const float* __restrict__ qn_g,
                            unsigned long long* __restrict__ partial) {
    const int yq    = blockIdx.x;
    const int n     = blockIdx.y;
    const int split = blockIdx.z;
    const int tid  = threadIdx.x;
    const int tx   = tid & 15;
    const int ty   = tid >> 4;
    const int i0   = ty * 4;
    const int jrow = tx >> 2;
    const int jx0  = (tx & 3) * 16;

    __shared__ float qS[C_][3][68];
    __shared__ float tS[C_][6][68];
    __shared__ float qnS[W_];

    const float* sb = s + n * (C_ * HW_);
    const float* tb = t + n * (C_ * HW_);

    #pragma unroll
    for (int k = 0; k < 3; ++k) {
        const int id = tid + k * 256;
        const int sg = id & 15;
        const int c  = (id >> 4) & 15;
        const int r  = id >> 8;
        const int gr = iclamp(yq + r - 1, 0, H_ - 1);
        const float4 v = *(const float4*)&sb[c * HW_ + gr * W_ + sg * 4];
        float* dst = &qS[c][r][1 + sg * 4];
        dst[0] = v.x; dst[1] = v.y; dst[2] = v.z; dst[3] = v.w;
    }
    if (tid < 48) {
        const int c  = tid & 15;
        const int r  = tid >> 4;
        const int gr = iclamp(yq + r - 1, 0, H_ - 1);
        qS[c][r][0]  = sb[c * HW_ + gr * W_];
        qS[c][r][65] = sb[c * HW_ + gr * W_ + 63];
    }
    if (tid < W_) qnS[tid] = qn_g[n * HW_ + yq * W_ + tid];

    unsigned long long best[4] = {~0ull, ~0ull, ~0ull, ~0ull};

    for (int ytl = 0; ytl < TILES_PER_SPLIT_V; ++ytl) {
        const int yt = split * TILES_PER_SPLIT_V + ytl;
        __syncthreads();
        #pragma unroll
        for (int k = 0; k < 6; ++k) {
            const int id = tid + k * 256;
            const int sg = id & 15;
            const int c  = (id >> 4) & 15;
            const int r  = id >> 8;
            const int gr = iclamp(4 * yt + r - 1, 0, H_ - 1);
            const float4 v = *(const float4*)&tb[c * HW_ + gr * W_ + sg * 4];
            float* dst = &tS[c][r][1 + sg * 4];
            dst[0] = v.x; dst[1] = v.y; dst[2] = v.z; dst[3] = v.w;
        }
        if (tid < 96) {
            const int c  = tid & 15;
            const int r  = tid >> 4;
            const int gr = iclamp(4 * yt + r - 1, 0, H_ - 1);
            tS[c][r][0]  = tb[c * HW_ + gr * W_];
            tS[c][r][65] = tb[c * HW_ + gr * W_ + 63];
        }
        __syncthreads();

        float acc[4][16];
        #pragma unroll
        for (int a = 0; a < 4; ++a)
            #pragma unroll
            for (int b = 0; b < 16; ++b) acc[a][b] = 0.f;

        for (int c = 0; c < C_; ++c) {
            #pragma unroll
            for (int dy = 0; dy < 3; ++dy) {
                float qv[6], tv[18];
                *(float4*)&qv[0] = *(const float4*)&qS[c][dy][i0];
                *(float2*)&qv[4] = *(const float2*)&qS[c][dy][i0 + 4];
                const float* trow = &tS[c][jrow + dy][jx0];
                *(float4*)&tv[0]  = *(const float4*)&trow[0];
                *(float4*)&tv[4]  = *(const float4*)&trow[4];
                *(float4*)&tv[8]  = *(const float4*)&trow[8];
                *(float4*)&tv[12] = *(const float4*)&trow[12];
                *(float2*)&tv[16] = *(const float2*)&trow[16];
                #pragma unroll
                for (int dx = 0; dx < 3; ++dx)
                    #pragma unroll
                    for (int a = 0; a < 4; ++a)
                        #pragma unroll
                        for (int b = 0; b < 16; ++b)
                            acc[a][b] += qv[a + dx] * tv[b + dx];
            }
        }

        const int jbase = yt * 256 + jrow * W_ + jx0;
        float pnv[16];
        const float* png = &pn_g[n * HW_ + jbase];
        *(float4*)&pnv[0]  = *(const float4*)&png[0];
        *(float4*)&pnv[4]  = *(const float4*)&png[4];
        *(float4*)&pnv[8]  = *(const float4*)&png[8];
        *(float4*)&pnv[12] = *(const float4*)&png[12];
        #pragma unroll
        for (int a = 0; a < 4; ++a) {
            const float qn = qnS[i0 + a];
            #pragma unroll
            for (int b = 0; b < 16; ++b) {
                const float d2 = qn + pnv[b] - 2.f * acc[a][b];
                unsigned long long cand =
                    ((unsigned long long)__float_as_uint(d2) << 32) |
                    (unsigned)(jbase + b);
                best[a] = cand < best[a] ? cand : best[a];
            }
        }
    }

    #pragma unroll
    for (int a = 0; a < 4; ++a) {
        unsigned long long v = best[a];
        #pragma unroll
        for (int mm = 8; mm >= 1; mm >>= 1) {
            unsigned long long o = __shfl_xor(v, mm, 64);
            v = o < v ? o : v;
        }
        best[a] = v;
    }
    if (tx == 0) {
        #pragma unroll
        for (int a = 0; a < 4; ++a)
            partial[((split * N_ + n) * HW_) + yq * W_ + i0 + a] = best[a];
    }
}

__global__ __launch_bounds__(256)
void finalize_kernel(const unsigned long long* __restrict__ partial,
                     float* __restrict__ out) {
    const int id  = blockIdx.x * 256 + threadIdx.x;
    const int n   = id >> 12;
    const int pix = id & 4095;
    unsigned long long best = ~0ull;
    #pragma unroll
    for (int sp = 0; sp < SPLITS_V; ++sp) {
        unsigned long long v = partial[(sp * N_ + n) * HW_ + pix];
        best = v < best ? v : best;
    }
    const unsigned j = (unsigned)(best & 0xffffffffu);
    const float d2 = __uint_as_float((unsigned)(best >> 32));
    out[n * 2 * HW_ + pix]            = (float)(j >> 6);
    out[n * 2 * HW_ + HW_ + pix]      = (float)(j & 63);
    out[N_ * 2 * HW_ + n * HW_ + pix] = d2;
}

__global__ __launch_bounds__(256)
void patchmatch_mono_kernel(const float* __restrict__ s,
                            const float* __restrict__ t,
                            float* __restrict__ out) {
    const int yq  = blockIdx.x;
    const int n   = blockIdx.y;
    const int tid = threadIdx.x;
    const int tx  = tid & 15;
    const int ty  = tid >> 4;
    const int i0  = ty * 4;
    const int jrow = tx >> 3;
    const int jx0  = (tx & 7) * 8;

    __shared__ float qS[C_][3][68];
    __shared__ float tS[C_][4][68];
    __shared__ float pnS[HW_];
    __shared__ float qnS[W_];

    const float* sb = s + n * (C_ * HW_);
    const float* tb = t + n * (C_ * HW_);

    for (int jj = tid; jj < HW_; jj += 256) {
        const int y = jj >> 6, x = jj & 63;
        float acc = 0.f;
        for (int c = 0; c < C_; ++c) {
            const float* tc = tb + c * HW_;
            #pragma unroll
            for (int dy = 0; dy < 3; ++dy) {
                const float* tr = tc + iclamp(y + dy - 1, 0, H_ - 1) * W_;
                #pragma unroll
                for (int dx = 0; dx < 3; ++dx) {
                    float v = tr[iclamp(x + dx - 1, 0, W_ - 1)];
                    acc += v * v;
                }
            }
        }
        pnS[jj] = acc;
    }
    for (int idx = tid; idx < C_ * 3 * 66; idx += 256) {
        const int c   = idx / (3 * 66);
        const int rem = idx - c * (3 * 66);
        const int rr  = rem / 66;
        const int xi  = rem - rr * 66;
        qS[c][rr][xi] = sb[c * HW_ + iclamp(yq + rr - 1, 0, H_ - 1) * W_ +
                           iclamp(xi - 1, 0, W_ - 1)];
    }
    __syncthreads();
    if (tid < W_) {
        float acc = 0.f;
        for (int c = 0; c < C_; ++c)
            #pragma unroll
            for (int dy = 0; dy < 3; ++dy)
                #pragma unroll
                for (int dx = 0; dx < 3; ++dx) {
                    float v = qS[c][dy][tid + dx];
                    acc += v * v;
                }
        qnS[tid] = acc;
    }

    unsigned long long best[4] = {~0ull, ~0ull, ~0ull, ~0ull};
    for (int yt = 0; yt < 32; ++yt) {
        __syncthreads();
        for (int idx = tid; idx < C_ * 4 * 66; idx += 256) {
            const int c   = idx / (4 * 66);
            const int rem = idx - c * (4 * 66);
            const int rr  = rem / 66;
            const int xi  = rem - rr * 66;
            tS[c][rr][xi] = tb[c * HW_ + iclamp(2 * yt + rr - 1, 0, H_ - 1) * W_ +
                               iclamp(xi - 1, 0, W_ - 1)];
        }
        __syncthreads();

        float acc[4][8];
        #pragma unroll
        for (int a = 0; a < 4; ++a)
            #pragma unroll
            for (int b = 0; b < 8; ++b) acc[a][b] = 0.f;

        for (int c = 0; c < C_; ++c) {
            #pragma unroll
            for (int dy = 0; dy < 3; ++dy) {
                float qv[8], tv[12];
                *(float4*)&qv[0] = *(const float4*)&qS[c][dy][i0];
                *(float4*)&qv[4] = *(const float4*)&qS[c][dy][i0 + 4];
                const float* trow = &tS[c][jrow + dy][jx0];
                *(float4*)&tv[0] = *(const float4*)&trow[0];
                *(float4*)&tv[4] = *(const float4*)&trow[4];
                *(float4*)&tv[8] = *(const float4*)&trow[8];
                #pragma unroll
                for (int dx = 0; dx < 3; ++dx)
                    #pragma unroll
                    for (int a = 0; a < 4; ++a)
                        #pragma unroll
                        for (int b = 0; b < 8; ++b)
                            acc[a][b] += qv[a + dx] * tv[b + dx];
            }
        }
        const int rbase = (2 * yt + jrow) * W_ + jx0;
        #pragma unroll
        for (int a = 0; a < 4; ++a) {
            const float qn = qnS[i0 + a];
            #pragma unroll
            for (int b = 0; b < 8; ++b) {
                const int j = rbase + b;
                const float d2 = qn + pnS[j] - 2.f * acc[a][b];
                unsigned long long cand =
                    ((unsigned long long)__float_as_uint(d2) << 32) | (unsigned)j;
                best[a] = cand < best[a] ? cand : best[a];
            }
        }
    }
    #pragma unroll
    for (int a = 0; a < 4; ++a) {
        unsigned long long v = best[a];
        #pragma unroll
        for (int mm = 8; mm >= 1; mm >>= 1) {
            unsigned long long o = __shfl_xor(v, mm, 64);
            v = o < v ? o : v;
        }
        best[a] = v;
    }
    if (tx == 0) {
        #pragma unroll
        for (int a = 0; a < 4; ++a) {
            const int x = i0 + a;
            const unsigned j = (unsigned)(best[a] & 0xffffffffu);
            const float d2 = __uint_as_float((unsigned)(best[a] >> 32));
            const int pix = yq * W_ + x;
            out[n * 2 * HW_ + pix]            = (float)(j >> 6);
            out[n * 2 * HW_ + HW_ + pix]      = (float)(j & 63);
            out[N_ * 2 * HW_ + n * HW_ + pix] = d2;
        }
    }
}

// ===========================================================================
extern "C" void kernel_launch(void* const* d_in, const int* in_sizes, int n_in,
                              void* d_out, int out_size, void* d_ws, size_t ws_size,
                              hipStream_t stream) {
    const float* s = (const float*)d_in[0];
    const float* t = (const float*)d_in[1];
    float* out = (float*)d_out;

    // MFMA ws layout:
    //   pn [4][4096] f32 | qn [4][4096] f32 | partial [8][4][4096] u64 |
    //   Qh | Ql | Ph | Pl   each [4][4096][160] f16
    const size_t norm_b  = (size_t)N_ * HW_ * 4;
    const size_t part_b  = (size_t)SPLITS_M * N_ * HW_ * 8;
    const size_t desc_b  = (size_t)N_ * HW_ * K_ * 2;
    const size_t need_m  = 2 * norm_b + part_b + 4 * desc_b;     // ~22 MB

    if (ws_size >= need_m) {
        char* w = (char*)d_ws;
        float* pn = (float*)w;                       w += norm_b;
        float* qn = (float*)w;                       w += norm_b;
        unsigned long long* partial = (unsigned long long*)w; w += part_b;
        f16* Qh = (f16*)w;  w += desc_b;
        f16* Ql = (f16*)w;  w += desc_b;
        f16* Ph = (f16*)w;  w += desc_b;
        f16* Pl = (f16*)w;

        build_desc_norms_kernel<<<dim3(64, N_, 2), 256, 0, stream>>>(
            s, t, Qh, Ql, Ph, Pl, pn, qn);
        mfma_nn_kernel<<<dim3(32, N_, SPLITS_M), 256, 0, stream>>>(
            Qh, Ql, Ph, Pl, pn, partial);
        finalize_mfma_kernel<<<64, 256, 0, stream>>>(partial, qn, out);
        return;
    }

    // Fallback: fp32 vector path
    const size_t need_v = 2 * norm_b + (size_t)SPLITS_V * N_ * HW_ * 8;
    if (ws_size >= need_v) {
        float* pn = (float*)d_ws;
        float* qn = pn + N_ * HW_;
        unsigned long long* partial =
            (unsigned long long*)((char*)d_ws + 2 * norm_b);
        prep_norms_kernel<<<128, 256, 0, stream>>>(s, t, pn, qn);
        dim3 grid(H_, N_, SPLITS_V);
        patchmatch_main_kernel<<<grid, 256, 0, stream>>>(s, t, pn, qn, partial);
        finalize_kernel<<<64, 256, 0, stream>>>(partial, out);
        return;
    }

    dim3 grid(H_, N_);
    patchmatch_mono_kernel<<<grid, 256, 0, stream>>>(s, t, out);
}